// Round 3
// baseline (30.513 us; speedup 1.0000x reference)
//
#include <hip/hip_runtime.h>

#define SIM_T 0.8f

// ---------------------------------------------------------------------------
// Vector path: every global load is an aligned, lane-contiguous float4.
//
// grid = B * parts blocks, 256 threads; per_part = NQ*1024 elements per block.
// Output rows start at odd flat offset (row*(K+1)+1), so per-row we shift the
// output quad grid by d = (-(row+1))&3 to restore 16B alignment. cos quads sit
// at shift 0; the keep-mask bits are passed through LDS (byte per quad) and
// recombined with a per-row nibble shift. Head elements j<d are handled in the
// final kernel; tail elements j>=K are masked here.
// ---------------------------------------------------------------------------
template <int NQ>
__global__ __launch_bounds__(256) void pruner_partial_v4(
    const float* __restrict__ out, const float* __restrict__ cs,
    float* __restrict__ ws, int K, int parts, int B) {
  const int per_part = NQ * 1024;          // elements per block
  const int nquads   = per_part / 4;       // quads per block
  const int row  = blockIdx.x / parts;
  const int part = blockIdx.x % parts;
  const int tid  = threadIdx.x;
  const int d    = (-(row + 1)) & 3;       // output quad-grid shift, uniform per block

  const float* crow  = cs  + (size_t)row * K + (size_t)part * per_part;
  // output quad s covers j = part*per_part + d + 4s .. +3 (flat: 16B-aligned)
  const float* obase = out + (size_t)row * (K + 1) + 1 + (size_t)part * per_part + d;

  __shared__ unsigned int mask_w[(NQ * 256) / 4 + 1];  // nibble-per-quad, byte-packed

  // ---- issue output loads first (oldest in flight, consumed last) ----
  float4 ov[NQ];
#pragma unroll
  for (int i = 0; i < NQ; ++i) {
    const int s = i * 256 + tid;
    ov[i] = *reinterpret_cast<const float4*>(obase + 4 * s);
  }
  // ---- cos loads ----
  float4 cv[NQ];
#pragma unroll
  for (int i = 0; i < NQ; ++i) {
    const int q = i * 256 + tid;
    cv[i] = *reinterpret_cast<const float4*>(crow + 4 * q);
  }
  // boundary quad (first quad of the next part/row region), thread 0 only
  if (tid == 0) {
    const float* pex = crow + per_part;
    if (row == B - 1 && part == parts - 1) pex = crow + per_part - 4;  // avoid OOB page
    const float4 ce = *reinterpret_cast<const float4*>(pex);
    const unsigned int nib = (ce.x < SIM_T ? 1u : 0u) | (ce.y < SIM_T ? 2u : 0u) |
                             (ce.z < SIM_T ? 4u : 0u) | (ce.w < SIM_T ? 8u : 0u);
    reinterpret_cast<unsigned char*>(mask_w)[nquads] = (unsigned char)nib;
  }
  // ---- pack keep-bits into LDS ----
#pragma unroll
  for (int i = 0; i < NQ; ++i) {
    const int q = i * 256 + tid;
    const unsigned int nib = (cv[i].x < SIM_T ? 1u : 0u) | (cv[i].y < SIM_T ? 2u : 0u) |
                             (cv[i].z < SIM_T ? 4u : 0u) | (cv[i].w < SIM_T ? 8u : 0u);
    reinterpret_cast<unsigned char*>(mask_w)[q] = (unsigned char)nib;
  }
  __syncthreads();

  // ---- masked exp-sum over the shifted output quads ----
  const bool lastpart = (part == parts - 1);
  float a0 = 0.f, a1 = 0.f, a2 = 0.f, a3 = 0.f;
#pragma unroll
  for (int i = 0; i < NQ; ++i) {
    const int s = i * 256 + tid;
    const unsigned int w0 = mask_w[s >> 2];
    const unsigned int w1 = mask_w[(s + 1) >> 2];
    const unsigned int nib0 = (w0 >> ((s & 3) * 8)) & 0xFu;
    const unsigned int nib1 = (w1 >> (((s + 1) & 3) * 8)) & 0xFu;
    unsigned int m = ((nib0 >> d) | (nib1 << (4 - d))) & 0xFu;
    if (lastpart && s == nquads - 1) m &= (0xFu >> d);  // exclude j >= K
    a0 += (m & 1u) ? __expf(ov[i].x) : 0.f;
    a1 += (m & 2u) ? __expf(ov[i].y) : 0.f;
    a2 += (m & 4u) ? __expf(ov[i].z) : 0.f;
    a3 += (m & 8u) ? __expf(ov[i].w) : 0.f;
  }
  float s = (a0 + a1) + (a2 + a3);

#pragma unroll
  for (int off = 32; off > 0; off >>= 1) s += __shfl_down(s, off, 64);

  __shared__ float lds[4];
  if ((tid & 63) == 0) lds[tid >> 6] = s;
  __syncthreads();
  if (tid == 0) ws[blockIdx.x] = (lds[0] + lds[1]) + (lds[2] + lds[3]);
}

// ---------------------------------------------------------------------------
// Generic fallback (scalar output loads) — only used for unexpected shapes.
// Covers all j in [0, K); head_in_final must be 0 when this ran.
// ---------------------------------------------------------------------------
__global__ __launch_bounds__(256) void pruner_partial_simple(
    const float* __restrict__ out, const float* __restrict__ cs,
    float* __restrict__ ws, int K, int parts) {
  const int per_part = K / parts;
  const int row  = blockIdx.x / parts;
  const int part = blockIdx.x % parts;
  const int tid  = threadIdx.x;
  const float* crow = cs  + (size_t)row * K + (size_t)part * per_part;
  const float* orow = out + (size_t)row * (K + 1) + 1 + (size_t)part * per_part;
  float a = 0.f;
  for (int k = tid; k < per_part; k += 256)
    a += (crow[k] < SIM_T) ? __expf(orow[k]) : 0.f;
#pragma unroll
  for (int off = 32; off > 0; off >>= 1) a += __shfl_down(a, off, 64);
  __shared__ float lds[4];
  if ((tid & 63) == 0) lds[tid >> 6] = a;
  __syncthreads();
  if (tid == 0) ws[blockIdx.x] = (lds[0] + lds[1]) + (lds[2] + lds[3]);
}

// ---------------------------------------------------------------------------
// Final: thread i folds row i's partials (+ head elements j<d when the vector
// path ran, + the always-kept positive logit), then block-reduces the mean.
// ---------------------------------------------------------------------------
__global__ __launch_bounds__(256) void pruner_final(
    const float* __restrict__ out, const float* __restrict__ cs,
    const float* __restrict__ ws, float* __restrict__ res,
    int K, int parts, int B, int head_in_final) {
  const int i = threadIdx.x;  // row
  float loss = 0.0f;
  if (i < B) {
    float t = 0.0f;
    for (int p = 0; p < parts; ++p) t += ws[i * parts + p];
    const float o0 = out[(size_t)i * (K + 1)];
    t += __expf(o0);
    if (head_in_final) {
      const int d = (-(i + 1)) & 3;
      for (int j = 0; j < d; ++j) {
        const float c = cs[(size_t)i * K + j];
        const float x = out[(size_t)i * (K + 1) + 1 + j];
        t += (c < SIM_T) ? __expf(x) : 0.f;
      }
    }
    loss = logf(t) - o0;
  }
#pragma unroll
  for (int off = 32; off > 0; off >>= 1) loss += __shfl_down(loss, off, 64);
  __shared__ float lds[4];
  if ((i & 63) == 0) lds[i >> 6] = loss;
  __syncthreads();
  if (i == 0) res[0] = ((lds[0] + lds[1]) + (lds[2] + lds[3])) / (float)B;
}

extern "C" void kernel_launch(void* const* d_in, const int* in_sizes, int n_in,
                              void* d_out, int out_size, void* d_ws, size_t ws_size,
                              hipStream_t stream) {
  const float* out = (const float*)d_in[0];   // [B, K+1] f32
  const float* cs  = (const float*)d_in[1];   // [B, K]   f32
  float* res = (float*)d_out;                 // scalar f32

  const int B = in_sizes[2];                  // 256
  const int K = in_sizes[1] / B;              // 65536
  float* ws = (float*)d_ws;

  constexpr int NQ = 4;                       // quads per thread per array
  const int chunk = NQ * 1024;                // 4096 elements per block
  if (B <= 256 && K % chunk == 0) {
    const int parts = K / chunk;              // 16 -> 4096 blocks
    pruner_partial_v4<NQ><<<B * parts, 256, 0, stream>>>(out, cs, ws, K, parts, B);
    pruner_final<<<1, 256, 0, stream>>>(out, cs, ws, res, K, parts, B, 1);
  } else {
    const int parts = 8;
    pruner_partial_simple<<<B * parts, 256, 0, stream>>>(out, cs, ws, K, parts);
    pruner_final<<<1, 256, 0, stream>>>(out, cs, ws, res, K, parts, B, 0);
  }
}

// Round 5
// 26.156 us; speedup vs baseline: 1.1666x; 1.1666x over previous
//
#include <hip/hip_runtime.h>

#define SIM_T 0.8f

typedef float f32x4 __attribute__((ext_vector_type(4)));

__device__ __forceinline__ f32x4 ntload4(const float* p) {
  return __builtin_nontemporal_load(reinterpret_cast<const f32x4*>(p));
}
__device__ __forceinline__ float ntload1(const float* p) {
  return __builtin_nontemporal_load(p);
}

// Kernel 1: per (row, part) masked sum of exp(output[row, 1+k]) over the
// part's slice, keeping only k where cos[row, k] < SIM_T.
// R2 structure (best so far) + nontemporal loads (streaming, use-once data)
// + o0 staging so the final kernel never does strided loads.
// grid = B*parts blocks, 256 threads; per_part = K/parts (multiple of 4096).
__global__ __launch_bounds__(256) void pruner_partial(
    const float* __restrict__ out, const float* __restrict__ cs,
    float* __restrict__ ws, float* __restrict__ o0s, int K, int parts) {
  const int per_part = K / parts;          // 8192
  const int row  = blockIdx.x / parts;
  const int part = blockIdx.x % parts;
  const int tid  = threadIdx.x;

  const float* crow = cs  + (size_t)row * K + (size_t)part * per_part;
  const float* orow = out + (size_t)row * (K + 1) + 1 + (size_t)part * per_part;

  // stage the positive logit for the final kernel (coalesced there)
  if (part == 0 && tid == 0) o0s[row] = orow[-1];

  float a0 = 0.f, a1 = 0.f, a2 = 0.f, a3 = 0.f;

  for (int kb = tid * 4; kb < per_part; kb += 4096) {
    // ---- issue all loads first (nontemporal: evict-first, use-once) ----
    f32x4 c0 = ntload4(crow + kb);
    f32x4 c1 = ntload4(crow + kb + 1024);
    f32x4 c2 = ntload4(crow + kb + 2048);
    f32x4 c3 = ntload4(crow + kb + 3072);
    float x00 = ntload1(orow + kb +    0), x01 = ntload1(orow + kb +    1);
    float x02 = ntload1(orow + kb +    2), x03 = ntload1(orow + kb +    3);
    float x10 = ntload1(orow + kb + 1024), x11 = ntload1(orow + kb + 1025);
    float x12 = ntload1(orow + kb + 1026), x13 = ntload1(orow + kb + 1027);
    float x20 = ntload1(orow + kb + 2048), x21 = ntload1(orow + kb + 2049);
    float x22 = ntload1(orow + kb + 2050), x23 = ntload1(orow + kb + 2051);
    float x30 = ntload1(orow + kb + 3072), x31 = ntload1(orow + kb + 3073);
    float x32 = ntload1(orow + kb + 3074), x33 = ntload1(orow + kb + 3075);
    // ---- then compute ----
    a0 += (c0.x < SIM_T) ? __expf(x00) : 0.f;
    a1 += (c0.y < SIM_T) ? __expf(x01) : 0.f;
    a2 += (c0.z < SIM_T) ? __expf(x02) : 0.f;
    a3 += (c0.w < SIM_T) ? __expf(x03) : 0.f;
    a0 += (c1.x < SIM_T) ? __expf(x10) : 0.f;
    a1 += (c1.y < SIM_T) ? __expf(x11) : 0.f;
    a2 += (c1.z < SIM_T) ? __expf(x12) : 0.f;
    a3 += (c1.w < SIM_T) ? __expf(x13) : 0.f;
    a0 += (c2.x < SIM_T) ? __expf(x20) : 0.f;
    a1 += (c2.y < SIM_T) ? __expf(x21) : 0.f;
    a2 += (c2.z < SIM_T) ? __expf(x22) : 0.f;
    a3 += (c2.w < SIM_T) ? __expf(x23) : 0.f;
    a0 += (c3.x < SIM_T) ? __expf(x30) : 0.f;
    a1 += (c3.y < SIM_T) ? __expf(x31) : 0.f;
    a2 += (c3.z < SIM_T) ? __expf(x32) : 0.f;
    a3 += (c3.w < SIM_T) ? __expf(x33) : 0.f;
  }
  float s = (a0 + a1) + (a2 + a3);

#pragma unroll
  for (int off = 32; off > 0; off >>= 1) s += __shfl_down(s, off, 64);

  __shared__ float lds[4];
  if ((tid & 63) == 0) lds[tid >> 6] = s;
  __syncthreads();
  if (tid == 0) ws[blockIdx.x] = (lds[0] + lds[1]) + (lds[2] + lds[3]);
}

// Generic fallback for shapes where per_part % 4096 != 0.
__global__ __launch_bounds__(256) void pruner_partial_simple(
    const float* __restrict__ out, const float* __restrict__ cs,
    float* __restrict__ ws, float* __restrict__ o0s, int K, int parts) {
  const int per_part = K / parts;
  const int row  = blockIdx.x / parts;
  const int part = blockIdx.x % parts;
  const int tid  = threadIdx.x;
  const float* crow = cs  + (size_t)row * K + (size_t)part * per_part;
  const float* orow = out + (size_t)row * (K + 1) + 1 + (size_t)part * per_part;
  if (part == 0 && tid == 0) o0s[row] = orow[-1];
  float a = 0.f;
  for (int k = tid; k < per_part; k += 256)
    a += (crow[k] < SIM_T) ? __expf(orow[k]) : 0.f;
#pragma unroll
  for (int off = 32; off > 0; off >>= 1) a += __shfl_down(a, off, 64);
  __shared__ float lds[4];
  if ((tid & 63) == 0) lds[tid >> 6] = a;
  __syncthreads();
  if (tid == 0) ws[blockIdx.x] = (lds[0] + lds[1]) + (lds[2] + lds[3]);
}

// Kernel 2: one block of B threads; everything it reads is coalesced
// (partials + staged o0). Thread i -> row i; block-reduce the mean.
__global__ __launch_bounds__(256) void pruner_final(
    const float* __restrict__ ws, const float* __restrict__ o0s,
    float* __restrict__ res, int parts, int B) {
  const int i = threadIdx.x;  // row
  float loss = 0.0f;
  if (i < B) {
    float t = 0.0f;
    for (int p = 0; p < parts; ++p) t += ws[i * parts + p];
    const float o0 = o0s[i];
    t += __expf(o0);
    loss = logf(t) - o0;
  }
#pragma unroll
  for (int off = 32; off > 0; off >>= 1) loss += __shfl_down(loss, off, 64);
  __shared__ float lds[4];
  if ((i & 63) == 0) lds[i >> 6] = loss;
  __syncthreads();
  if (i == 0) res[0] = ((lds[0] + lds[1]) + (lds[2] + lds[3])) / (float)B;
}

extern "C" void kernel_launch(void* const* d_in, const int* in_sizes, int n_in,
                              void* d_out, int out_size, void* d_ws, size_t ws_size,
                              hipStream_t stream) {
  const float* out = (const float*)d_in[0];   // [B, K+1] f32
  const float* cs  = (const float*)d_in[1];   // [B, K]   f32
  float* res = (float*)d_out;                 // scalar f32

  const int B = in_sizes[2];                  // 256
  const int K = in_sizes[1] / B;              // 65536

  const int PARTS = 8;                        // 2048 blocks = 8/CU
  float* ws  = (float*)d_ws;                  // [B*PARTS] partials
  float* o0s = ws + (size_t)B * PARTS;        // [B] staged positive logits

  if ((K / PARTS) % 4096 == 0) {
    pruner_partial<<<B * PARTS, 256, 0, stream>>>(out, cs, ws, o0s, K, PARTS);
  } else {
    pruner_partial_simple<<<B * PARTS, 256, 0, stream>>>(out, cs, ws, o0s, K, PARTS);
  }
  pruner_final<<<1, 256, 0, stream>>>(ws, o0s, res, PARTS, B);
}